// Round 6
// baseline (2909.735 us; speedup 1.0000x reference)
//
#include <hip/hip_runtime.h>
#include <hip/hip_bf16.h>

typedef __hip_bfloat16 bf16;
typedef short s8 __attribute__((ext_vector_type(8)));
typedef short sv4 __attribute__((ext_vector_type(4)));
typedef float f4 __attribute__((ext_vector_type(4)));

#define BETA 0.125f
#define EPS 1e-5f

__device__ __forceinline__ void gld16(const void* g, void* l){
    __builtin_amdgcn_global_load_lds(
        (const __attribute__((address_space(1))) void*)g,
        (__attribute__((address_space(3))) void*)l, 16, 0, 0);
}

// ---------- converts ----------
__global__ __launch_bounds__(256) void f2b_k(const float* __restrict__ in, bf16* __restrict__ out, long n){
    long i = (long)blockIdx.x*256 + threadIdx.x;
    if (i < n) out[i] = __float2bfloat16(in[i]);
}
__global__ __launch_bounds__(256) void padx_k(const float* __restrict__ x, bf16* __restrict__ xb){
    long i = (long)blockIdx.x*256 + threadIdx.x;
    if (i >= 6400L*768) return;
    long row = i / 768;
    xb[i] = (row < 6272) ? __float2bfloat16(x[i]) : __float2bfloat16(0.f);
}
__global__ __launch_bounds__(256) void tr_k(const short* __restrict__ Bi, short* __restrict__ Bo){
    __shared__ short t[32][33];
    int i0 = blockIdx.x*32, j0 = blockIdx.y*32;
    int li = threadIdx.x & 31, lj = threadIdx.x >> 5;
    #pragma unroll
    for (int r=0;r<4;r++) t[lj+8*r][li] = Bi[(long)(i0+lj+8*r)*768 + j0+li];
    __syncthreads();
    #pragma unroll
    for (int r=0;r<4;r++) Bo[(long)(j0+lj+8*r)*4608 + i0+li] = t[li][lj+8*r];
}

// ---------- cls row init ----------
__global__ __launch_bounds__(256) void cls_k(const float* __restrict__ cls, const float* __restrict__ pos,
                                             float* __restrict__ t){
    int i = blockIdx.x*256 + threadIdx.x;
    int b = i / 768, c = i % 768;
    t[((long)b*197)*768 + c] = cls[c] + pos[c];
}

// ---------- big MFMA GEMM (128x128 tile; used for encode/decode epilogues) ----------
// MODE 2: encode epilogue | MODE 3: decode epilogue
template<int MODE>
__global__ __launch_bounds__(256) void big_gemm(
    const short* __restrict__ A, int lda,
    const short* __restrict__ B, int ldb,
    float* __restrict__ Cf, bf16* __restrict__ Cb, int ldc,
    int K, int Nn, int Nm, int relu0, long zoff,
    const float* __restrict__ bias, const float* __restrict__ pos)
{
    const int f = blockIdx.x;
    const int npg = 16*Nn;
    const int grp = f / npg;
    const int first_m = grp*16;
    const int gs = (Nm - first_m < 16) ? (Nm - first_m) : 16;
    const int rem = f % npg;
    const int bm = first_m + rem % gs;
    const int bn = rem / gs;

    __shared__ short lsA[8192];   // 2 k-panels x (128 rows x 32 cols)
    __shared__ short lsB[8192];
    const int tid = threadIdx.x;
    const int w = tid>>6, l = tid&63;
    const int m0 = bm*128, n0 = bn*128;
    const int srow = tid>>2;                       // 0..63 (global row within half)
    const int qglob = ((tid&3) - (tid>>3)) & 3;    // swizzled source quadrant
    const int scol = qglob*8;                      // shorts
    int koff, Ks;
    if (MODE==1){ Ks = K>>1; koff = blockIdx.z * Ks; Cf += (size_t)blockIdx.z * zoff; }
    else        { Ks = K;    koff = 0; }
    const short* pa = A + (size_t)(m0+srow)*lda + koff + scol;
    const short* pb = B + (size_t)(n0+srow)*ldb + koff + scol;
    short* laP = lsA + w*512;
    short* lbP = lsB + w*512;
    const int wm = (w>>1)*64, wn = (w&1)*64;
    const int fr = l&15, fq = ((l>>4) + (fr>>1) & 3)*8;   // swizzled read quadrant
    f4 acc[4][4] = {};
    const int nk = Ks>>6;
    for (int kt=0; kt<nk; kt++){
        const size_t ko = (size_t)kt*64;
        const size_t ra = 64*(size_t)lda, rb = 64*(size_t)ldb;
        gld16(pa + ko,           laP);
        gld16(pa + ko + ra,      laP + 2048);
        gld16(pa + ko + 32,      laP + 4096);
        gld16(pa + ko + 32 + ra, laP + 6144);
        gld16(pb + ko,           lbP);
        gld16(pb + ko + rb,      lbP + 2048);
        gld16(pb + ko + 32,      lbP + 4096);
        gld16(pb + ko + 32 + rb, lbP + 6144);
        __syncthreads();
        #pragma unroll
        for (int ks=0; ks<2; ks++){
            s8 af[4], bfr[4];
            #pragma unroll
            for (int i=0;i<4;i++) af[i]  = *(const s8*)(lsA + ks*4096 + (wm+i*16+fr)*32 + fq);
            #pragma unroll
            for (int j=0;j<4;j++) bfr[j] = *(const s8*)(lsB + ks*4096 + (wn+j*16+fr)*32 + fq);
            #pragma unroll
            for (int i=0;i<4;i++)
                #pragma unroll
                for (int j=0;j<4;j++)
                    acc[i][j] = __builtin_amdgcn_mfma_f32_16x16x32_bf16(af[i], bfr[j], acc[i][j], 0,0,0);
        }
        __syncthreads();
    }
    const int er = (l>>4)*4;
    const int ec = l&15;
    #pragma unroll
    for (int i=0;i<4;i++){
        #pragma unroll
        for (int j=0;j<4;j++){
            int gr0 = m0 + wm + i*16 + er;
            int gc  = n0 + wn + j*16 + ec;
            #pragma unroll
            for (int r=0;r<4;r++){
                float v = acc[i][j][r];
                int gr = gr0 + r;
                if (MODE==0){
                    if (gc >= relu0) v = v>0.f ? v : 0.f;
                    Cb[(size_t)gr*ldc + gc] = __float2bfloat16(v);
                } else if (MODE==1){
                    Cf[(size_t)gr*ldc + gc] = v;
                } else if (MODE==2){
                    if (gr < 6272){
                        int b = gr/196, n = gr%196;
                        Cf[((size_t)b*197 + n + 1)*768 + gc] = v + bias[gc] + pos[(long)(n+1)*768+gc];
                    }
                } else {
                    if (gr < 6272) Cf[(size_t)gr*ldc + gc] = v + bias[gc];
                }
            }
        }
    }
}

// ---------- 4-phase 256x256 MFMA GEMM: C = A[M,K] @ B[N,K]^T ----------
// BM=BN=256, BK=64, 512 threads = 8 waves (2M x 4N), wave tile 128x64
// (acc 8x4 - same per-wave math as the proven wide_gemm). Double-buffered
// 128 KB LDS (1 block/CU). Per K-tile, FOUR phases; the ONLY vmcnt drain is
// the single boundary __syncthreads:
//   P1: stage next-tile A (4 gld16)          + ks0/i-half0 (8 ds_read,16 MFMA)
//   P2: stage next-tile B-h0 (2 gld16)       + ks0/i-half1 (4 ds_read,16 MFMA)
//   P3: stage next-tile B-h1 (2 gld16)       + ks1/i-half0 (8 ds_read,16 MFMA)
//   P4:                                        ks1/i-half1 (4 ds_read,16 MFMA)
//   __syncthreads  [stages issued 1-3 phases (~620-2500cy MFMA) earlier
//                   >= ~900cy HBM latency -> drain is cheap]
// Phases separated by raw s_barrier (pacing only, no drain); setprio(1)
// around MFMA clusters. Correctness rests ONLY on the boundary __syncthreads:
// stages target buf^1 exclusively, whose last reads completed before the
// previous boundary barrier. R5 FIX: LDS dest of gld16 is WAVE-UNIFORM
// (plane + w*512 shorts; HW places lane l at +l*16B) -- r4 passed a
// lane-divergent pointer (tid*8), risking a backend waterfall loop.
// LDS layout per buf: [half h][ks plane][128 rows][4 quads][8 shorts] -- the
// 64B ks-plane rows reuse wide_gemm/big_gemm's measured-zero-conflict quadrant
// swizzle verbatim (stage qs = ((tid&3)-(tid>>3))&3; read fq = (lq+(fr>>1))&3).
// MODE 0: C bf16, relu col>=relu0 | MODE 1: fp32 partials, K split 3 ways by
// blockIdx.z; z==2 writes Cf2 (third partial in scratch aliasing qT/kT).
template<int MODE>
__global__ __launch_bounds__(512) void gem8(
    const short* __restrict__ A, int lda,
    const short* __restrict__ B, int ldb,
    float* __restrict__ Cf, float* __restrict__ Cf2,
    bf16* __restrict__ Cb, int ldc,
    int K, int Nn, int Nm, int relu0, long zoff)
{
    const int f = blockIdx.x;
    const int npg = 16*Nn;
    const int grp = f / npg;
    const int first_m = grp*16;
    const int gs = (Nm - first_m < 16) ? (Nm - first_m) : 16;
    const int rem = f % npg;
    const int bm = first_m + rem % gs;
    const int bn = rem / gs;

    __shared__ short lsA[32768];  // 2 bufs x [2 half][2 ks][128 rows][32 shorts] = 64 KB
    __shared__ short lsB[32768];
    const int tid = threadIdx.x;
    const int w = tid>>6, l = tid&63;
    const int m0 = bm*256, n0 = bn*256;

    int Ks, koff; float* Cp = Cf;
    if (MODE==1){ Ks = K/3; koff = blockIdx.z * Ks;
                  Cp = (blockIdx.z==2) ? Cf2 : Cf + (size_t)blockIdx.z * zoff; }
    else        { Ks = K; koff = 0; }
    const int NT = Ks>>6;   // BK=64

    // Staging (per thread): thread tid covers LDS chunk tid of each
    // [half][ks] plane; row = tid>>2, dest quad = tid&3, source quad
    // qs = ((tid&3)-(tid>>3))&3 (proven swizzle). LDS dest passed to gld16 is
    // the WAVE-uniform chunk base (w*512 shorts); HW adds lane*16B.
    const int srow = tid>>2;                       // 0..127 (row within plane)
    const int qs = ((tid&3) - (tid>>3)) & 3;
    const short* pa = A + (size_t)(m0+srow)*lda + koff + qs*8;
    const short* pb = B + (size_t)(n0+srow)*ldb + koff + qs*8;
    const int wds = w*512;                         // wave chunk base, shorts

    #define STA(S,H,KS,KT) gld16(pa + (size_t)(H)*128*lda + (size_t)(KT)*64 + (KS)*32, \
                                 lsA + (S)*16384 + (H)*8192 + (KS)*4096 + wds)
    #define STB(S,H,KS,KT) gld16(pb + (size_t)(H)*128*ldb + (size_t)(KT)*64 + (KS)*32, \
                                 lsB + (S)*16384 + (H)*8192 + (KS)*4096 + wds)

    const int wm = (w>>2)*128, wn = (w&3)*64;
    const int hA = wm>>7;          // A half owned by this wave
    const int hB = wn>>7;          // B half owned by this wave
    const int wnl = wn & 64;       // row base within B half
    const int fr = l&15, lq = l>>4;
    const int fq = ((lq + (fr>>1)) & 3)*8;        // swizzled read quadrant
    f4 acc[8][4] = {};

    // prologue: K-tile 0 -> buf 0, single full drain
    STA(0,0,0,0); STA(0,0,1,0); STA(0,1,0,0); STA(0,1,1,0);
    STB(0,0,0,0); STB(0,0,1,0); STB(0,1,0,0); STB(0,1,1,0);
    __syncthreads();

    int s = 0;
    for (int kt=0; kt<NT; kt++){
        const int nx = (kt+1 < NT);
        const short* aB = lsA + s*16384 + hA*8192;
        const short* bB = lsB + s*16384 + hB*8192;
        s8 af[4], bfr[4];
        // ---- P1: stage A(next) ; compute ks0, i-half0 ----
        if (nx){ STA(s^1,0,0,kt+1); STA(s^1,0,1,kt+1); STA(s^1,1,0,kt+1); STA(s^1,1,1,kt+1); }
        __builtin_amdgcn_sched_barrier(0);
        #pragma unroll
        for (int i=0;i<4;i++) af[i]  = *(const s8*)(aB + (i*16+fr)*32 + fq);
        #pragma unroll
        for (int j=0;j<4;j++) bfr[j] = *(const s8*)(bB + (wnl+j*16+fr)*32 + fq);
        __builtin_amdgcn_s_setprio(1);
        #pragma unroll
        for (int i=0;i<4;i++)
            #pragma unroll
            for (int j=0;j<4;j++)
                acc[i][j] = __builtin_amdgcn_mfma_f32_16x16x32_bf16(af[i], bfr[j], acc[i][j], 0,0,0);
        __builtin_amdgcn_s_setprio(0);
        __builtin_amdgcn_s_barrier();
        // ---- P2: stage B-h0(next) ; compute ks0, i-half1 (reuse bfr) ----
        if (nx){ STB(s^1,0,0,kt+1); STB(s^1,0,1,kt+1); }
        __builtin_amdgcn_sched_barrier(0);
        #pragma unroll
        for (int i=0;i<4;i++) af[i] = *(const s8*)(aB + ((64+i*16)+fr)*32 + fq);
        __builtin_amdgcn_s_setprio(1);
        #pragma unroll
        for (int i=0;i<4;i++)
            #pragma unroll
            for (int j=0;j<4;j++)
                acc[4+i][j] = __builtin_amdgcn_mfma_f32_16x16x32_bf16(af[i], bfr[j], acc[4+i][j], 0,0,0);
        __builtin_amdgcn_s_setprio(0);
        __builtin_amdgcn_s_barrier();
        // ---- P3: stage B-h1(next) ; compute ks1, i-half0 ----
        if (nx){ STB(s^1,1,0,kt+1); STB(s^1,1,1,kt+1); }
        __builtin_amdgcn_sched_barrier(0);
        #pragma unroll
        for (int i=0;i<4;i++) af[i]  = *(const s8*)(aB + 4096 + (i*16+fr)*32 + fq);
        #pragma unroll
        for (int j=0;j<4;j++) bfr[j] = *(const s8*)(bB + 4096 + (wnl+j*16+fr)*32 + fq);
        __builtin_amdgcn_s_setprio(1);
        #pragma unroll
        for (int i=0;i<4;i++)
            #pragma unroll
            for (int j=0;j<4;j++)
                acc[i][j] = __builtin_amdgcn_mfma_f32_16x16x32_bf16(af[i], bfr[j], acc[i][j], 0,0,0);
        __builtin_amdgcn_s_setprio(0);
        __builtin_amdgcn_s_barrier();
        // ---- P4: compute ks1, i-half1 ----
        #pragma unroll
        for (int i=0;i<4;i++) af[i] = *(const s8*)(aB + 4096 + ((64+i*16)+fr)*32 + fq);
        __builtin_amdgcn_s_setprio(1);
        #pragma unroll
        for (int i=0;i<4;i++)
            #pragma unroll
            for (int j=0;j<4;j++)
                acc[4+i][j] = __builtin_amdgcn_mfma_f32_16x16x32_bf16(af[i], bfr[j], acc[4+i][j], 0,0,0);
        __builtin_amdgcn_s_setprio(0);
        __syncthreads();   // the ONE drain per K-tile; stages are 1-3 phases old
        s ^= 1;
    }
    #undef STA
    #undef STB

    const int er = lq*4;
    const int ec = l&15;
    #pragma unroll
    for (int i=0;i<8;i++){
        #pragma unroll
        for (int j=0;j<4;j++){
            int gr0 = m0 + wm + i*16 + er;
            int gc  = n0 + wn + j*16 + ec;
            #pragma unroll
            for (int r=0;r<4;r++){
                float v = acc[i][j][r];
                int gr = gr0 + r;
                if (MODE==0){
                    if (gc >= relu0) v = v>0.f ? v : 0.f;
                    Cb[(size_t)gr*ldc + gc] = __float2bfloat16(v);
                } else {
                    Cp[(size_t)gr*ldc + gc] = v;
                }
            }
        }
    }
}

// ---------- pack q^T / k^T : [384][64 z][256 m] bf16, zero-padded ----------
__global__ __launch_bounds__(256) void pack_k(const short* __restrict__ qkh,
                                              short* __restrict__ qT, short* __restrict__ kT){
    __shared__ short tq[64][65];
    __shared__ short tk[64][65];
    const int bh = blockIdx.x, b = bh/12, h = bh%12;
    const int mc = blockIdx.y*64;
    const int tid = threadIdx.x;
    #pragma unroll
    for (int e=0;e<16;e++){
        int i = tid + e*256; int r = i>>6, c = i&63;
        int mg = mc + r;
        short vq = 0, vk = 0;
        if (mg < 197){
            size_t base = (size_t)(b*197+mg)*4608 + h*64 + c;
            vq = qkh[base]; vk = qkh[base+768];
        }
        tq[r][c] = vq; tk[r][c] = vk;
    }
    __syncthreads();
    #pragma unroll
    for (int e=0;e<16;e++){
        int i = tid + e*256; int zr = i>>6, cm = i&63;
        size_t o = (size_t)bh*16384 + (size_t)zr*256 + mc + cm;
        qT[o] = tq[cm][zr];
        kT[o] = tk[cm][zr];
    }
}

// ---------- fused attention per (b,h) ----------
__global__ __launch_bounds__(256) void attn_k(
    short* __restrict__ qkh, const short* __restrict__ qT, const short* __restrict__ kT)
{
    __shared__ short Pl[64*232];
    __shared__ short Ptl[208*72];
    const int bh = blockIdx.x, b = bh/12, h = bh%12;
    const int tid = threadIdx.x, w = tid>>6, l = tid&63;
    const int lr = l&15, lq = l>>4;
    const size_t qcol = (size_t)h*64, kcol = 768 + qcol;
    const size_t rbase = (size_t)b*197*4608;
    const short* qTp = qT + (size_t)bh*16384;
    const short* kTp = kT + (size_t)bh*16384;

    for (int i=tid; i<64*16; i+=256){ int r=i>>4, c=208+(i&15); Pl[r*232+c]=0; }

    f4 ak[13];
    #pragma unroll
    for (int t=0;t<13;t++) ak[t] = (f4){0.f,0.f,0.f,0.f};

    for (int iter=0; iter<4; iter++){
        const int m0 = iter*64;
        f4 S[13];
        #pragma unroll
        for (int t=0;t<13;t++) S[t] = (f4){0.f,0.f,0.f,0.f};
        const int mrow = m0 + w*16 + lr;
        #pragma unroll
        for (int ks=0; ks<2; ks++){
            s8 af = *(const s8*)(qkh + rbase + (size_t)mrow*4608 + qcol + ks*32 + lq*8);
            #pragma unroll
            for (int t=0;t<13;t++){
                s8 bf = *(const s8*)(qkh + rbase + (size_t)(t*16+lr)*4608 + kcol + ks*32 + lq*8);
                S[t] = __builtin_amdgcn_mfma_f32_16x16x32_bf16(af, bf, S[t], 0,0,0);
            }
        }
        __syncthreads();
        const int mbase = w*16 + lq*4;
        #pragma unroll
        for (int r=0;r<4;r++){
            float mx = -1e30f;
            #pragma unroll
            for (int t=0;t<13;t++){
                float v = S[t][r]*BETA;
                if (t==12 && lr>=5) v = -1e30f;
                S[t][r] = v;
                mx = fmaxf(mx, v);
            }
            mx = fmaxf(mx, __shfl_xor(mx,1,64)); mx = fmaxf(mx, __shfl_xor(mx,2,64));
            mx = fmaxf(mx, __shfl_xor(mx,4,64)); mx = fmaxf(mx, __shfl_xor(mx,8,64));
            float sm = 0.f;
            #pragma unroll
            for (int t=0;t<13;t++){ float e = __expf(S[t][r]-mx); S[t][r]=e; sm+=e; }
            sm += __shfl_xor(sm,1,64); sm += __shfl_xor(sm,2,64);
            sm += __shfl_xor(sm,4,64); sm += __shfl_xor(sm,8,64);
            float inv = 1.f/sm;
            bool valid = (m0 + mbase + r) < 197;
            #pragma unroll
            for (int t=0;t<13;t++) S[t][r] = valid ? S[t][r]*inv : 0.f;
        }
        #pragma unroll
        for (int t=0;t<13;t++){
            int c = t*16 + lr;
            short pb[4];
            #pragma unroll
            for (int r=0;r<4;r++){
                bf16 bv = __float2bfloat16(S[t][r]);
                pb[r] = *(short*)&bv;
                Pl[(mbase+r)*232 + c] = pb[r];
            }
            *(sv4*)(Ptl + c*72 + mbase) = (sv4){pb[0],pb[1],pb[2],pb[3]};
        }
        __syncthreads();
        f4 aq[4];
        #pragma unroll
        for (int t=0;t<4;t++) aq[t] = (f4){0.f,0.f,0.f,0.f};
        #pragma unroll
        for (int ks=0; ks<7; ks++){
            s8 af = *(const s8*)(kTp + (w*16+lr)*256 + ks*32 + lq*8);
            #pragma unroll
            for (int mt=0;mt<4;mt++){
                s8 bf = *(const s8*)(Pl + (mt*16+lr)*232 + ks*32 + lq*8);
                aq[mt] = __builtin_amdgcn_mfma_f32_16x16x32_bf16(af, bf, aq[mt], 0,0,0);
            }
        }
        #pragma unroll
        for (int mt=0;mt<4;mt++){
            int mg = m0 + mt*16 + lr;
            if (mg < 197){
                sv4 pv;
                #pragma unroll
                for (int r=0;r<4;r++){ bf16 bv=__float2bfloat16(aq[mt][r]); pv[r]=*(short*)&bv; }
                *(sv4*)(qkh + rbase + (size_t)mg*4608 + qcol + w*16 + lq*4) = pv;
            }
        }
        #pragma unroll
        for (int ks=0; ks<2; ks++){
            s8 bf = *(const s8*)(qTp + (w*16+lr)*256 + m0 + ks*32 + lq*8);
            #pragma unroll
            for (int t=0;t<13;t++){
                s8 af = *(const s8*)(Ptl + (t*16+lr)*72 + ks*32 + lq*8);
                ak[t] = __builtin_amdgcn_mfma_f32_16x16x32_bf16(af, bf, ak[t], 0,0,0);
            }
        }
    }
    #pragma unroll
    for (int t=0;t<13;t++){
        #pragma unroll
        for (int r=0;r<4;r++){
            int n = t*16 + lq*4 + r;
            if (n < 197)
                *(bf16*)(qkh + rbase + (size_t)n*4608 + kcol + w*16 + lr) = __float2bfloat16(ak[t][r]);
        }
    }
}

// ---------- LN (optionally folds 3 split-K partials into t first) ----------
__global__ __launch_bounds__(256) void ln_k(
    float* __restrict__ in, bf16* __restrict__ out,
    const float* __restrict__ p0, const float* __restrict__ p1, const float* __restrict__ p2,
    const float* __restrict__ scale, const float* __restrict__ bias,
    int scalar_scale, int rowmap, int addp, int writet)
{
    int r = blockIdx.x;
    long src = rowmap ? ((long)(r/196)*197 + r%196 + 1) : (long)r;
    float* xr = in + src*768;
    int tid = threadIdx.x;
    float v0 = xr[tid], v1 = xr[tid+256], v2 = xr[tid+512];
    if (addp){
        const float* a = p0 + src*768;
        const float* b = p1 + src*768;
        const float* c = p2 + src*768;
        v0 += a[tid]     + b[tid]     + c[tid];
        v1 += a[tid+256] + b[tid+256] + c[tid+256];
        v2 += a[tid+512] + b[tid+512] + c[tid+512];
        if (writet){ xr[tid]=v0; xr[tid+256]=v1; xr[tid+512]=v2; }
    }
    __shared__ float red[4];
    float s = v0+v1+v2;
    #pragma unroll
    for (int o=1;o<64;o<<=1) s += __shfl_xor(s, o, 64);
    if ((tid&63)==0) red[tid>>6] = s;
    __syncthreads();
    float mu = (red[0]+red[1]+red[2]+red[3]) * (1.f/768.f);
    float d0=v0-mu, d1=v1-mu, d2=v2-mu;
    float q = d0*d0 + d1*d1 + d2*d2;
    #pragma unroll
    for (int o=1;o<64;o<<=1) q += __shfl_xor(q, o, 64);
    __syncthreads();
    if ((tid&63)==0) red[tid>>6] = q;
    __syncthreads();
    float ms = (red[0]+red[1]+red[2]+red[3]) * (1.f/768.f);
    float inv = rsqrtf(ms + EPS);
    bf16* o_ = out + (long)r*768;
    float s0 = scalar_scale ? scale[0] : scale[tid];
    float s1 = scalar_scale ? s0 : scale[tid+256];
    float s2 = scalar_scale ? s0 : scale[tid+512];
    o_[tid]     = __float2bfloat16(d0*inv*s0 + bias[tid]);
    o_[tid+256] = __float2bfloat16(d1*inv*s1 + bias[tid+256]);
    o_[tid+512] = __float2bfloat16(d2*inv*s2 + bias[tid+512]);
}

extern "C" void kernel_launch(void* const* d_in, const int* in_sizes, int n_in,
                              void* d_out, int out_size, void* d_ws, size_t ws_size,
                              hipStream_t stream) {
    const float* x       = (const float*)d_in[0];
    const float* w_enc   = (const float*)d_in[1];
    const float* b_enc   = (const float*)d_in[2];
    const float* cls_tok = (const float*)d_in[3];
    const float* pos     = (const float*)d_in[4];
    const float* eln_g   = (const float*)d_in[5];
    const float* eln_b   = (const float*)d_in[6];
    const float* wq      = (const float*)d_in[7];
    const float* wk      = (const float*)d_in[8];
    const float* w_hop   = (const float*)d_in[9];
    const float* dln_w   = (const float*)d_in[10];
    const float* dln_b   = (const float*)d_in[11];
    const float* w_dec   = (const float*)d_in[12];
    const float* b_dec   = (const float*)d_in[13];
    float* out = (float*)d_out;

    float* t_  = (float*)d_ws;                    // [6400,768] fp32
    bf16* g_   = (bf16*)(t_ + 6400L*768);         // [6400,768]
    bf16* qkh  = g_ + 6400L*768;                  // [6400,4608] = q|k|h (aq|ak overwrite q|k)
    bf16* qT   = qkh + 6400L*4608;                // [384,64,256]
    bf16* kT   = qT + 384L*16384;                 // [384,64,256]
    float* p0  = (float*)(kT + 384L*16384);       // [6400,768] split-K partial z=0
    float* p1  = p0 + 6400L*768;                  // [6400,768] split-K partial z=1
    bf16* B1   = (bf16*)(p1 + 6400L*768);         // [4608,768]  wq|wk|whop
    bf16* B2   = B1 + 4608L*768;                  // [768,4608]  = B1^T
    bf16* we_  = B2 + 768L*4608;                  // [768,768]
    bf16* wd_  = we_ + 768L*768;                  // [768,768]
    // z=2 partial aliases qT/kT scratch: that region (25.2 MB >= 19.7 MB) is
    // dead between attn_k (last reader) and the next step's pack_k (next
    // writer); gem8<1> fills it fully before ln_k reads it.
    float* p2  = (float*)qT;

    dim3 blk(256);
    const long ZOFF = 6400L*768;

    f2b_k<<<dim3((589824+255)/256),  blk, 0, stream>>>(wq,    B1,          589824);
    f2b_k<<<dim3((589824+255)/256),  blk, 0, stream>>>(wk,    B1+589824,   589824);
    f2b_k<<<dim3((2359296+255)/256), blk, 0, stream>>>(w_hop, B1+1179648, 2359296);
    f2b_k<<<dim3((589824+255)/256),  blk, 0, stream>>>(w_enc, we_,         589824);
    f2b_k<<<dim3((589824+255)/256),  blk, 0, stream>>>(w_dec, wd_,         589824);
    tr_k<<<dim3(144,24), blk, 0, stream>>>((const short*)B1, (short*)B2);
    padx_k<<<dim3((int)((6400L*768+255)/256)), blk, 0, stream>>>(x, g_);

    cls_k<<<dim3(96), blk, 0, stream>>>(cls_tok, pos, t_);
    big_gemm<2><<<dim3(300), blk, 0, stream>>>((const short*)g_, 768, (const short*)we_, 768,
                                               t_, nullptr, 768, 768, 6, 50, 0, 0, b_enc, pos);

    for (int step=0; step<12; step++){
        ln_k<<<dim3(6304), blk, 0, stream>>>(t_, g_, p0, p1, p2, eln_g, eln_b, 1, 0, step>0, 1);
        // [6400,4608] = g @ [wq|wk|whop]^T, K=768: 25m x 18n = 450 blocks
        gem8<0><<<dim3(450), dim3(512), 0, stream>>>((const short*)g_, 768, (const short*)B1, 768,
                                                     nullptr, nullptr, qkh, 4608, 768, 18, 25, 1536, 0);
        pack_k<<<dim3(384,4), blk, 0, stream>>>((const short*)qkh, (short*)qT, (short*)kT);
        attn_k<<<dim3(384), blk, 0, stream>>>((short*)qkh, (const short*)qT, (const short*)kT);
        // [6400,768] = [aq|ak|relu h] @ B2^T-form, K=4608 split 3: 25m x 3n x 3z
        gem8<1><<<dim3(75,1,3), dim3(512), 0, stream>>>((const short*)qkh, 4608, (const short*)B2, 4608,
                                                        p0, p2, nullptr, 768, 4608, 3, 25, 0, ZOFF);
    }

    ln_k<<<dim3(6272), blk, 0, stream>>>(t_, g_, p0, p1, p2, dln_w, dln_b, 0, 1, 1, 0);
    big_gemm<3><<<dim3(300), blk, 0, stream>>>((const short*)g_, 768, (const short*)wd_, 768,
                                               out, nullptr, 768, 768, 6, 50, 0, 0, b_dec, nullptr);
}

// Round 8
// 2391.802 us; speedup vs baseline: 1.2165x; 1.2165x over previous
//
#include <hip/hip_runtime.h>
#include <hip/hip_bf16.h>

typedef __hip_bfloat16 bf16;
typedef short s8 __attribute__((ext_vector_type(8)));
typedef short sv4 __attribute__((ext_vector_type(4)));
typedef float f4 __attribute__((ext_vector_type(4)));

#define BETA 0.125f
#define EPS 1e-5f

__device__ __forceinline__ void gld16(const void* g, void* l){
    __builtin_amdgcn_global_load_lds(
        (const __attribute__((address_space(1))) void*)g,
        (__attribute__((address_space(3))) void*)l, 16, 0, 0);
}

// ---------- fused prologue: all fp32->bf16 weight converts + x pad + cls row ----------
// segments (element index e over one flat grid; TOTAL = 9,658,368 = 37728*256):
//   [0,589824)           wq    -> B1
//   [589824,1179648)     wk    -> B1+589824
//   [1179648,3538944)    w_hop -> B1+1179648
//   [3538944,4128768)    w_enc -> we
//   [4128768,4718592)    w_dec -> wd
//   [4718592,9633792)    x     -> g (rows >=6272 zero-padded)   [4915200 elems]
//   [9633792,9658368)    cls+pos -> t row 0 of each batch (fp32) [24576 = 32*768]
// R7 BUG FIX: grid was 37920 (cls tail 3x too long, b up to 95 -> OOB fp32
// writes over g_). Grid now 37728 AND the cls branch is guarded b<32 so the
// kernel is correct for any covering grid.
__global__ __launch_bounds__(256) void pre_k(
    const float* __restrict__ wq, const float* __restrict__ wk, const float* __restrict__ w_hop,
    const float* __restrict__ w_enc, const float* __restrict__ w_dec,
    const float* __restrict__ x, const float* __restrict__ cls, const float* __restrict__ pos,
    bf16* __restrict__ B1, bf16* __restrict__ we_, bf16* __restrict__ wd_,
    bf16* __restrict__ g_, float* __restrict__ t_)
{
    long e = (long)blockIdx.x*256 + threadIdx.x;
    if (e < 3538944L){
        float v;
        if (e < 589824L)        v = wq[e];
        else if (e < 1179648L)  v = wk[e - 589824L];
        else                    v = w_hop[e - 1179648L];
        B1[e] = __float2bfloat16(v);
    } else if (e < 4128768L){
        long i = e - 3538944L;  we_[i] = __float2bfloat16(w_enc[i]);
    } else if (e < 4718592L){
        long i = e - 4128768L;  wd_[i] = __float2bfloat16(w_dec[i]);
    } else if (e < 9633792L){
        long i = e - 4718592L;
        long row = i / 768;
        g_[i] = (row < 6272) ? __float2bfloat16(x[i]) : __float2bfloat16(0.f);
    } else {
        long i = e - 9633792L;
        int b = (int)(i / 768), c = (int)(i % 768);
        if (b < 32) t_[((long)b*197)*768 + c] = cls[c] + pos[c];
    }
}

__global__ __launch_bounds__(256) void tr_k(const short* __restrict__ Bi, short* __restrict__ Bo){
    __shared__ short t[32][33];
    int i0 = blockIdx.x*32, j0 = blockIdx.y*32;
    int li = threadIdx.x & 31, lj = threadIdx.x >> 5;
    #pragma unroll
    for (int r=0;r<4;r++) t[lj+8*r][li] = Bi[(long)(i0+lj+8*r)*768 + j0+li];
    __syncthreads();
    #pragma unroll
    for (int r=0;r<4;r++) Bo[(long)(j0+lj+8*r)*4608 + i0+li] = t[li][lj+8*r];
}

// ---------- big MFMA GEMM (128x128 tile; used for encode/decode epilogues) ----------
// MODE 2: encode epilogue | MODE 3: decode epilogue
template<int MODE>
__global__ __launch_bounds__(256) void big_gemm(
    const short* __restrict__ A, int lda,
    const short* __restrict__ B, int ldb,
    float* __restrict__ Cf, bf16* __restrict__ Cb, int ldc,
    int K, int Nn, int Nm, int relu0, long zoff,
    const float* __restrict__ bias, const float* __restrict__ pos)
{
    const int f = blockIdx.x;
    const int npg = 16*Nn;
    const int grp = f / npg;
    const int first_m = grp*16;
    const int gs = (Nm - first_m < 16) ? (Nm - first_m) : 16;
    const int rem = f % npg;
    const int bm = first_m + rem % gs;
    const int bn = rem / gs;

    __shared__ short lsA[8192];   // 2 k-panels x (128 rows x 32 cols)
    __shared__ short lsB[8192];
    const int tid = threadIdx.x;
    const int w = tid>>6, l = tid&63;
    const int m0 = bm*128, n0 = bn*128;
    const int srow = tid>>2;                       // 0..63 (global row within half)
    const int qglob = ((tid&3) - (tid>>3)) & 3;    // swizzled source quadrant
    const int scol = qglob*8;                      // shorts
    int koff, Ks;
    if (MODE==1){ Ks = K>>1; koff = blockIdx.z * Ks; Cf += (size_t)blockIdx.z * zoff; }
    else        { Ks = K;    koff = 0; }
    const short* pa = A + (size_t)(m0+srow)*lda + koff + scol;
    const short* pb = B + (size_t)(n0+srow)*ldb + koff + scol;
    short* laP = lsA + w*512;
    short* lbP = lsB + w*512;
    const int wm = (w>>1)*64, wn = (w&1)*64;
    const int fr = l&15, fq = ((l>>4) + (fr>>1) & 3)*8;   // swizzled read quadrant
    f4 acc[4][4] = {};
    const int nk = Ks>>6;
    for (int kt=0; kt<nk; kt++){
        const size_t ko = (size_t)kt*64;
        const size_t ra = 64*(size_t)lda, rb = 64*(size_t)ldb;
        gld16(pa + ko,           laP);
        gld16(pa + ko + ra,      laP + 2048);
        gld16(pa + ko + 32,      laP + 4096);
        gld16(pa + ko + 32 + ra, laP + 6144);
        gld16(pb + ko,           lbP);
        gld16(pb + ko + rb,      lbP + 2048);
        gld16(pb + ko + 32,      lbP + 4096);
        gld16(pb + ko + 32 + rb, lbP + 6144);
        __syncthreads();
        #pragma unroll
        for (int ks=0; ks<2; ks++){
            s8 af[4], bfr[4];
            #pragma unroll
            for (int i=0;i<4;i++) af[i]  = *(const s8*)(lsA + ks*4096 + (wm+i*16+fr)*32 + fq);
            #pragma unroll
            for (int j=0;j<4;j++) bfr[j] = *(const s8*)(lsB + ks*4096 + (wn+j*16+fr)*32 + fq);
            #pragma unroll
            for (int i=0;i<4;i++)
                #pragma unroll
                for (int j=0;j<4;j++)
                    acc[i][j] = __builtin_amdgcn_mfma_f32_16x16x32_bf16(af[i], bfr[j], acc[i][j], 0,0,0);
        }
        __syncthreads();
    }
    const int er = (l>>4)*4;
    const int ec = l&15;
    #pragma unroll
    for (int i=0;i<4;i++){
        #pragma unroll
        for (int j=0;j<4;j++){
            int gr0 = m0 + wm + i*16 + er;
            int gc  = n0 + wn + j*16 + ec;
            #pragma unroll
            for (int r=0;r<4;r++){
                float v = acc[i][j][r];
                int gr = gr0 + r;
                if (MODE==0){
                    if (gc >= relu0) v = v>0.f ? v : 0.f;
                    Cb[(size_t)gr*ldc + gc] = __float2bfloat16(v);
                } else if (MODE==1){
                    Cf[(size_t)gr*ldc + gc] = v;
                } else if (MODE==2){
                    if (gr < 6272){
                        int b = gr/196, n = gr%196;
                        Cf[((size_t)b*197 + n + 1)*768 + gc] = v + bias[gc] + pos[(long)(n+1)*768+gc];
                    }
                } else {
                    if (gr < 6272) Cf[(size_t)gr*ldc + gc] = v + bias[gc];
                }
            }
        }
    }
}

// ---------- wide MFMA GEMM: C = A[M,K] @ B[N,K]^T  (round-2 verified, 60us) ----------
// BM=256, BN=128, BK=64, 256 threads = 4 waves (2M x 2N), WAVE TILE 128x64
// (8x4 16x16 fragments). Plain 2-barrier __syncthreads structure; 48KB LDS,
// 2 blocks/CU cross-block overlap. Hand-pipelined variants (r1 ring@1blk,
// r3 dbuf@BK32, r4 counted-ring@BK32, r6 4-phase) ALL regressed vs this.
// MODE 0: C bf16, relu col>=relu0 | MODE 1: fp32 partials, K split 3 ways by
// blockIdx.z; z==2 writes Cf2 (third partial in scratch aliasing qT/kT).
template<int MODE>
__global__ __launch_bounds__(256, 2) void wide_gemm(
    const short* __restrict__ A, int lda,
    const short* __restrict__ B, int ldb,
    float* __restrict__ Cf, float* __restrict__ Cf2,
    bf16* __restrict__ Cb, int ldc,
    int K, int Nn, int Nm, int relu0, long zoff)
{
    const int f = blockIdx.x;
    const int npg = 16*Nn;
    const int grp = f / npg;
    const int first_m = grp*16;
    const int gs = (Nm - first_m < 16) ? (Nm - first_m) : 16;
    const int rem = f % npg;
    const int bm = first_m + rem % gs;
    const int bn = rem / gs;

    __shared__ short lsA[16384];  // 2 k-panels x 256 rows x 32 shorts
    __shared__ short lsB[8192];   // 2 k-panels x 128 rows x 32 shorts
    const int tid = threadIdx.x;
    const int w = tid>>6, l = tid&63;
    const int m0 = bm*256, n0 = bn*128;

    int Ks, koff; float* Cp = Cf;
    if (MODE==1){ Ks = K/3; koff = blockIdx.z * Ks;
                  Cp = (blockIdx.z==2) ? Cf2 : Cf + (size_t)blockIdx.z * zoff; }
    else        { Ks = K; koff = 0; }
    const int NT = Ks>>6;

    // Staging: LDS layout [panel p][row r][quadrant qd][8 shorts], linear dest
    // = lane*16B per sweep. Sweep j covers chunks c=j*256+tid (p=0); the p=1
    // copy of the same (r,qd) is source+32 shorts -> folds into inst offset.
    // Bank swizzle: global quadrant qs=(qd-(r>>1))&3 lands at LDS quadrant qd.
    const short* sA[4]; const short* sB[2];
    #pragma unroll
    for (int j=0;j<4;j++){
        int c = j*256 + tid;
        int r = (c>>2)&255, qd = c&3;
        int qs = (qd - (r>>1)) & 3;
        sA[j] = A + (size_t)(m0+r)*lda + koff + qs*8;
    }
    #pragma unroll
    for (int j=0;j<2;j++){
        int c = j*256 + tid;
        int r = (c>>2)&127, qd = c&3;
        int qs = (qd - (r>>1)) & 3;
        sB[j] = B + (size_t)(n0+r)*ldb + koff + qs*8;
    }

    const int wm = (w>>1)*128, wn = (w&1)*64;
    const int fr = l&15;
    const int fq = (((l>>4) + (fr>>1)) & 3)*8;   // swizzled read quadrant
    f4 acc[8][4] = {};

    for (int kt=0; kt<NT; kt++){
        const size_t ko = (size_t)kt*64;
        short* dA = lsA + w*512;
        short* dB = lsB + w*512;
        #pragma unroll
        for (int j=0;j<4;j++){
            gld16(sA[j]+ko,      dA + j*2048);
            gld16(sA[j]+ko+32,   dA + (j+4)*2048);
        }
        #pragma unroll
        for (int j=0;j<2;j++){
            gld16(sB[j]+ko,      dB + j*2048);
            gld16(sB[j]+ko+32,   dB + (j+2)*2048);
        }
        __syncthreads();
        #pragma unroll
        for (int ks=0; ks<2; ks++){
            s8 af[8], bfr[4];
            #pragma unroll
            for (int i=0;i<8;i++) af[i]  = *(const s8*)(lsA + ks*8192 + (wm+i*16+fr)*32 + fq);
            #pragma unroll
            for (int j=0;j<4;j++) bfr[j] = *(const s8*)(lsB + ks*4096 + (wn+j*16+fr)*32 + fq);
            #pragma unroll
            for (int i=0;i<8;i++)
                #pragma unroll
                for (int j=0;j<4;j++)
                    acc[i][j] = __builtin_amdgcn_mfma_f32_16x16x32_bf16(af[i], bfr[j], acc[i][j], 0,0,0);
        }
        __syncthreads();
    }

    const int er = (l>>4)*4;
    const int ec = l&15;
    #pragma unroll
    for (int i=0;i<8;i++){
        #pragma unroll
        for (int j=0;j<4;j++){
            int gr0 = m0 + wm + i*16 + er;
            int gc  = n0 + wn + j*16 + ec;
            #pragma unroll
            for (int r=0;r<4;r++){
                float v = acc[i][j][r];
                int gr = gr0 + r;
                if (MODE==0){
                    if (gc >= relu0) v = v>0.f ? v : 0.f;
                    Cb[(size_t)gr*ldc + gc] = __float2bfloat16(v);
                } else {
                    Cp[(size_t)gr*ldc + gc] = v;
                }
            }
        }
    }
}

// ---------- pack q^T / k^T : [384][64 z][256 m] bf16, zero-padded ----------
__global__ __launch_bounds__(256) void pack_k(const short* __restrict__ qkh,
                                              short* __restrict__ qT, short* __restrict__ kT){
    __shared__ short tq[64][65];
    __shared__ short tk[64][65];
    const int bh = blockIdx.x, b = bh/12, h = bh%12;
    const int mc = blockIdx.y*64;
    const int tid = threadIdx.x;
    #pragma unroll
    for (int e=0;e<16;e++){
        int i = tid + e*256; int r = i>>6, c = i&63;
        int mg = mc + r;
        short vq = 0, vk = 0;
        if (mg < 197){
            size_t base = (size_t)(b*197+mg)*4608 + h*64 + c;
            vq = qkh[base]; vk = qkh[base+768];
        }
        tq[r][c] = vq; tk[r][c] = vk;
    }
    __syncthreads();
    #pragma unroll
    for (int e=0;e<16;e++){
        int i = tid + e*256; int zr = i>>6, cm = i&63;
        size_t o = (size_t)bh*16384 + (size_t)zr*256 + mc + cm;
        qT[o] = tq[cm][zr];
        kT[o] = tk[cm][zr];
    }
}

// ---------- fused attention per (b,h) ----------
__global__ __launch_bounds__(256) void attn_k(
    short* __restrict__ qkh, const short* __restrict__ qT, const short* __restrict__ kT)
{
    __shared__ short Pl[64*232];
    __shared__ short Ptl[208*72];
    const int bh = blockIdx.x, b = bh/12, h = bh%12;
    const int tid = threadIdx.x, w = tid>>6, l = tid&63;
    const int lr = l&15, lq = l>>4;
    const size_t qcol = (size_t)h*64, kcol = 768 + qcol;
    const size_t rbase = (size_t)b*197*4608;
    const short* qTp = qT + (size_t)bh*16384;
    const short* kTp = kT + (size_t)bh*16384;

    for (int i=tid; i<64*16; i+=256){ int r=i>>4, c=208+(i&15); Pl[r*232+c]=0; }

    f4 ak[13];
    #pragma unroll
    for (int t=0;t<13;t++) ak[t] = (f4){0.f,0.f,0.f,0.f};

    for (int iter=0; iter<4; iter++){
        const int m0 = iter*64;
        f4 S[13];
        #pragma unroll
        for (int t=0;t<13;t++) S[t] = (f4){0.f,0.f,0.f,0.f};
        const int mrow = m0 + w*16 + lr;
        #pragma unroll
        for (int ks=0; ks<2; ks++){
            s8 af = *(const s8*)(qkh + rbase + (size_t)mrow*4608 + qcol + ks*32 + lq*8);
            #pragma unroll
            for (int t=0;t<13;t++){
                s8 bf = *(const s8*)(qkh + rbase + (size_t)(t*16+lr)*4608 + kcol + ks*32 + lq*8);
                S[t] = __builtin_amdgcn_mfma_f32_16x16x32_bf16(af, bf, S[t], 0,0,0);
            }
        }
        __syncthreads();
        const int mbase = w*16 + lq*4;
        #pragma unroll
        for (int r=0;r<4;r++){
            float mx = -1e30f;
            #pragma unroll
            for (int t=0;t<13;t++){
                float v = S[t][r]*BETA;
                if (t==12 && lr>=5) v = -1e30f;
                S[t][r] = v;
                mx = fmaxf(mx, v);
            }
            mx = fmaxf(mx, __shfl_xor(mx,1,64)); mx = fmaxf(mx, __shfl_xor(mx,2,64));
            mx = fmaxf(mx, __shfl_xor(mx,4,64)); mx = fmaxf(mx, __shfl_xor(mx,8,64));
            float sm = 0.f;
            #pragma unroll
            for (int t=0;t<13;t++){ float e = __expf(S[t][r]-mx); S[t][r]=e; sm+=e; }
            sm += __shfl_xor(sm,1,64); sm += __shfl_xor(sm,2,64);
            sm += __shfl_xor(sm,4,64); sm += __shfl_xor(sm,8,64);
            float inv = 1.f/sm;
            bool valid = (m0 + mbase + r) < 197;
            #pragma unroll
            for (int t=0;t<13;t++) S[t][r] = valid ? S[t][r]*inv : 0.f;
        }
        #pragma unroll
        for (int t=0;t<13;t++){
            int c = t*16 + lr;
            short pb[4];
            #pragma unroll
            for (int r=0;r<4;r++){
                bf16 bv = __float2bfloat16(S[t][r]);
                pb[r] = *(short*)&bv;
                Pl[(mbase+r)*232 + c] = pb[r];
            }
            *(sv4*)(Ptl + c*72 + mbase) = (sv4){pb[0],pb[1],pb[2],pb[3]};
        }
        __syncthreads();
        f4 aq[4];
        #pragma unroll
        for (int t=0;t<4;t++) aq[t] = (f4){0.f,0.f,0.f,0.f};
        #pragma unroll
        for (int ks=0; ks<7; ks++){
            s8 af = *(const s8*)(kTp + (w*16+lr)*256 + ks*32 + lq*8);
            #pragma unroll
            for (int mt=0;mt<4;mt++){
                s8 bf = *(const s8*)(Pl + (mt*16+lr)*232 + ks*32 + lq*8);
                aq[mt] = __builtin_amdgcn_mfma_f32_16x16x32_bf16(af, bf, aq[mt], 0,0,0);
            }
        }
        #pragma unroll
        for (int mt=0;mt<4;mt++){
            int mg = m0 + mt*16 + lr;
            if (mg < 197){
                sv4 pv;
                #pragma unroll
                for (int r=0;r<4;r++){ bf16 bv=__float2bfloat16(aq[mt][r]); pv[r]=*(short*)&bv; }
                *(sv4*)(qkh + rbase + (size_t)mg*4608 + qcol + w*16 + lq*4) = pv;
            }
        }
        #pragma unroll
        for (int ks=0; ks<2; ks++){
            s8 bf = *(const s8*)(qTp + (w*16+lr)*256 + m0 + ks*32 + lq*8);
            #pragma unroll
            for (int t=0;t<13;t++){
                s8 af = *(const s8*)(Ptl + (t*16+lr)*72 + ks*32 + lq*8);
                ak[t] = __builtin_amdgcn_mfma_f32_16x16x32_bf16(af, bf, ak[t], 0,0,0);
            }
        }
    }
    #pragma unroll
    for (int t=0;t<13;t++){
        #pragma unroll
        for (int r=0;r<4;r++){
            int n = t*16 + lq*4 + r;
            if (n < 197)
                *(bf16*)(qkh + rbase + (size_t)n*4608 + kcol + w*16 + lr) = __float2bfloat16(ak[t][r]);
        }
    }
}

// ---------- LN (optionally folds 3 split-K partials into t first) ----------
__global__ __launch_bounds__(256) void ln_k(
    float* __restrict__ in, bf16* __restrict__ out,
    const float* __restrict__ p0, const float* __restrict__ p1, const float* __restrict__ p2,
    const float* __restrict__ scale, const float* __restrict__ bias,
    int scalar_scale, int rowmap, int addp, int writet)
{
    int r = blockIdx.x;
    long src = rowmap ? ((long)(r/196)*197 + r%196 + 1) : (long)r;
    float* xr = in + src*768;
    int tid = threadIdx.x;
    float v0 = xr[tid], v1 = xr[tid+256], v2 = xr[tid+512];
    if (addp){
        const float* a = p0 + src*768;
        const float* b = p1 + src*768;
        const float* c = p2 + src*768;
        v0 += a[tid]     + b[tid]     + c[tid];
        v1 += a[tid+256] + b[tid+256] + c[tid+256];
        v2 += a[tid+512] + b[tid+512] + c[tid+512];
        if (writet){ xr[tid]=v0; xr[tid+256]=v1; xr[tid+512]=v2; }
    }
    __shared__ float red[4];
    float s = v0+v1+v2;
    #pragma unroll
    for (int o=1;o<64;o<<=1) s += __shfl_xor(s, o, 64);
    if ((tid&63)==0) red[tid>>6] = s;
    __syncthreads();
    float mu = (red[0]+red[1]+red[2]+red[3]) * (1.f/768.f);
    float d0=v0-mu, d1=v1-mu, d2=v2-mu;
    float q = d0*d0 + d1*d1 + d2*d2;
    #pragma unroll
    for (int o=1;o<64;o<<=1) q += __shfl_xor(q, o, 64);
    __syncthreads();
    if ((tid&63)==0) red[tid>>6] = q;
    __syncthreads();
    float ms = (red[0]+red[1]+red[2]+red[3]) * (1.f/768.f);
    float inv = rsqrtf(ms + EPS);
    bf16* o_ = out + (long)r*768;
    float s0 = scalar_scale ? scale[0] : scale[tid];
    float s1 = scalar_scale ? s0 : scale[tid+256];
    float s2 = scalar_scale ? s0 : scale[tid+512];
    o_[tid]     = __float2bfloat16(d0*inv*s0 + bias[tid]);
    o_[tid+256] = __float2bfloat16(d1*inv*s1 + bias[tid+256]);
    o_[tid+512] = __float2bfloat16(d2*inv*s2 + bias[tid+512]);
}

extern "C" void kernel_launch(void* const* d_in, const int* in_sizes, int n_in,
                              void* d_out, int out_size, void* d_ws, size_t ws_size,
                              hipStream_t stream) {
    const float* x       = (const float*)d_in[0];
    const float* w_enc   = (const float*)d_in[1];
    const float* b_enc   = (const float*)d_in[2];
    const float* cls_tok = (const float*)d_in[3];
    const float* pos     = (const float*)d_in[4];
    const float* eln_g   = (const float*)d_in[5];
    const float* eln_b   = (const float*)d_in[6];
    const float* wq      = (const float*)d_in[7];
    const float* wk      = (const float*)d_in[8];
    const float* w_hop   = (const float*)d_in[9];
    const float* dln_w   = (const float*)d_in[10];
    const float* dln_b   = (const float*)d_in[11];
    const float* w_dec   = (const float*)d_in[12];
    const float* b_dec   = (const float*)d_in[13];
    float* out = (float*)d_out;

    float* t_  = (float*)d_ws;                    // [6400,768] fp32
    bf16* g_   = (bf16*)(t_ + 6400L*768);         // [6400,768]
    bf16* qkh  = g_ + 6400L*768;                  // [6400,4608] = q|k|h (aq|ak overwrite q|k)
    bf16* qT   = qkh + 6400L*4608;                // [384,64,256]
    bf16* kT   = qT + 384L*16384;                 // [384,64,256]
    float* p0  = (float*)(kT + 384L*16384);       // [6400,768] split-K partial z=0
    float* p1  = p0 + 6400L*768;                  // [6400,768] split-K partial z=1
    bf16* B1   = (bf16*)(p1 + 6400L*768);         // [4608,768]  wq|wk|whop
    bf16* B2   = B1 + 4608L*768;                  // [768,4608]  = B1^T
    bf16* we_  = B2 + 768L*4608;                  // [768,768]
    bf16* wd_  = we_ + 768L*768;                  // [768,768]
    // z=2 partial aliases qT/kT scratch: that region (25.2 MB >= 19.7 MB) is
    // dead between attn_k (last reader) and the next step's pack_k (next
    // writer); wide_gemm<1> fills it fully before ln_k reads it.
    float* p2  = (float*)qT;

    dim3 blk(256);
    const long ZOFF = 6400L*768;

    // fused prologue: 5 weight converts + x pad + cls row in ONE launch
    pre_k<<<dim3(37728), blk, 0, stream>>>(wq, wk, w_hop, w_enc, w_dec, x, cls_tok, pos,
                                           B1, we_, wd_, g_, t_);
    tr_k<<<dim3(144,24), blk, 0, stream>>>((const short*)B1, (short*)B2);

    big_gemm<2><<<dim3(300), blk, 0, stream>>>((const short*)g_, 768, (const short*)we_, 768,
                                               t_, nullptr, 768, 768, 6, 50, 0, 0, b_enc, pos);

    for (int step=0; step<12; step++){
        ln_k<<<dim3(6304), blk, 0, stream>>>(t_, g_, p0, p1, p2, eln_g, eln_b, 1, 0, step>0, 1);
        // [6400,4608] = g @ [wq|wk|whop]^T, K=768: 25 x 36 = 900 blocks
        wide_gemm<0><<<dim3(900), blk, 0, stream>>>((const short*)g_, 768, (const short*)B1, 768,
                                                    nullptr, nullptr, qkh, 4608, 768, 36, 25, 1536, 0);
        pack_k<<<dim3(384,4), blk, 0, stream>>>((const short*)qkh, (short*)qT, (short*)kT);
        attn_k<<<dim3(384), blk, 0, stream>>>((short*)qkh, (const short*)qT, (const short*)kT);
        // [6400,768] = [aq|ak|relu h] @ B2^T-form, K=4608 split 3: 150 x 3 blocks
        wide_gemm<1><<<dim3(150,1,3), blk, 0, stream>>>((const short*)qkh, 4608, (const short*)B2, 4608,
                                                        p0, p2, nullptr, 768, 4608, 6, 25, 0, ZOFF);
    }

    ln_k<<<dim3(6272), blk, 0, stream>>>(t_, g_, p0, p1, p2, dln_w, dln_b, 0, 1, 1, 0);
    big_gemm<3><<<dim3(300), blk, 0, stream>>>((const short*)g_, 768, (const short*)wd_, 768,
                                               out, nullptr, 768, 768, 6, 50, 0, 0, b_dec, nullptr);
}